// Round 1
// baseline (624.746 us; speedup 1.0000x reference)
//
#include <hip/hip_runtime.h>
#include <math.h>

#define NT 512
#define VV 128000
#define VW 4000        // VV/32 words of prompt bitmask
#define NB 128         // batch
#define PP 2048        // prompt len
#define OO 256         // output len
#define HS 1024        // hash slots
#define TC 8           // per-thread candidates
#define NC (NT*TC)     // 4096

#define BIG_NEG_F (-1e30f)
// packkey(-INF, 0x7fffffff)
#define PAD_KEY 0x007FFFFF80000000ULL

__device__ __forceinline__ unsigned long long packkey(float f, int idx) {
  unsigned int b = __float_as_uint(f);
  unsigned int mf = (b & 0x80000000u) ? ~b : (b | 0x80000000u);
  return ((unsigned long long)mf << 32) | (unsigned long long)(unsigned int)(~(unsigned int)idx);
}

__global__ __launch_bounds__(NT)
void sampler_kernel(const float* __restrict__ logits,
                    const int* __restrict__ prompt_ids,
                    const int* __restrict__ output_ids,
                    const int* __restrict__ stop_ids,
                    const int* __restrict__ min_tokens,
                    const float* __restrict__ presence_p,
                    const float* __restrict__ frequency_p,
                    const float* __restrict__ repetition_p,
                    const float* __restrict__ temperature,
                    const int* __restrict__ top_k,
                    const float* __restrict__ top_p,
                    const float* __restrict__ noise,
                    float* __restrict__ out, int K)
{
#pragma clang fp contract(off)
  __shared__ unsigned int pbits[VW];
  __shared__ int hkey[HS];
  __shared__ int hval[HS];
  __shared__ unsigned long long cand[NC];
  __shared__ float wsum[NT/64];
  __shared__ float sv[64];
  __shared__ int   si[64];
  __shared__ float sg[64];

  const int row = blockIdx.x;
  const int tid = threadIdx.x;
  if (row >= NB) return;

  const float fp  = frequency_p[row];
  const float pp  = presence_p[row];
  const float rp  = repetition_p[row];
  const float tpv = top_p[row];
  const float tmp = temperature[row];
  const float t   = (tmp < 1e-5f) ? 1.0f : tmp;
  const int   tk  = top_k[row];
  const bool need = min_tokens[row] > OO;
  const int s0 = stop_ids[row*4+0];
  const int s1 = stop_ids[row*4+1];
  const int s2 = stop_ids[row*4+2];
  const int s3 = stop_ids[row*4+3];

  // ---- init LDS structures ----
  for (int i = tid; i < VW; i += NT) pbits[i] = 0u;
  for (int i = tid; i < HS; i += NT) { hkey[i] = -1; hval[i] = 0; }
  __syncthreads();

  // prompt bitmask
  for (int i = tid; i < PP; i += NT) {
    int tok = prompt_ids[row*PP + i];
    atomicOr(&pbits[tok >> 5], 1u << (tok & 31));
  }
  // output counts hash
  for (int i = tid; i < OO; i += NT) {
    int tok = output_ids[row*OO + i];
    unsigned int h = ((unsigned int)tok * 2654435761u) >> 22;
    for (;;) {
      int k = hkey[h];
      if (k == tok) { atomicAdd(&hval[h], 1); break; }
      if (k == -1) {
        int prev = atomicCAS(&hkey[h], -1, tok);
        if (prev == -1 || prev == tok) { atomicAdd(&hval[h], 1); break; }
        continue;  // re-read slot: now holds another key -> will advance
      }
      h = (h + 1) & (HS - 1);
    }
  }
  __syncthreads();

  // ---- streaming pass over V: penalties, shifted exp-sum, per-thread top-8 ----
  unsigned long long loc[TC];
  #pragma unroll
  for (int c = 0; c < TC; c++) loc[c] = PAD_KEY;
  float s40 = 0.0f;

  const float* __restrict__ lrow = logits + (size_t)row * VV;
  for (int v = tid; v < VV; v += NT) {
    float x = lrow[v];
    if (need && ((v == s0) || (v == s1) || (v == s2) || (v == s3)))
      x = fminf(x, BIG_NEG_F);
    bool pm = (pbits[v >> 5] >> (v & 31)) & 1u;
    float cnt = 0.0f;
    unsigned int h = ((unsigned int)v * 2654435761u) >> 22;
    for (;;) {
      int k = hkey[h];
      if (k == -1) break;
      if (k == v) { cnt = (float)hval[h]; break; }
      h = (h + 1) & (HS - 1);
    }
    bool om = cnt > 0.0f;
    if (pm || om) x = (x > 0.0f) ? (x / rp) : (x * rp);
    x = x - fp * cnt;
    if (om) x = x - pp;
    x = x / t;

    s40 += expf(x - 40.0f);

    unsigned long long key = packkey(x, v);
    if (key > loc[TC-1]) {
      loc[TC-1] = key;
      #pragma unroll
      for (int q = TC - 1; q >= 1; q--) {
        if (loc[q] > loc[q-1]) {
          unsigned long long tsw = loc[q]; loc[q] = loc[q-1]; loc[q-1] = tsw;
        }
      }
    }
  }

  // dump candidates
  #pragma unroll
  for (int c = 0; c < TC; c++) cand[tid * TC + c] = loc[c];

  // reduce shifted exp-sum
  float s = s40;
  #pragma unroll
  for (int off = 32; off > 0; off >>= 1) s += __shfl_down(s, off, 64);
  if ((tid & 63) == 0) wsum[tid >> 6] = s;
  __syncthreads();

  // ---- bitonic sort (descending by value, ascending index on ties) ----
  for (int k = 2; k <= NC; k <<= 1) {
    for (int j = k >> 1; j > 0; j >>= 1) {
      for (int i = tid; i < NC; i += NT) {
        int ixj = i ^ j;
        if (ixj > i) {
          unsigned long long a = cand[i];
          unsigned long long b = cand[ixj];
          bool up = (i & k) == 0;
          if ((a < b) == up) { cand[i] = b; cand[ixj] = a; }
        }
      }
      __syncthreads();
    }
  }

  // ---- unpack top-64, gather noise ----
  if (tid < 64) {
    unsigned long long kk = cand[tid];
    unsigned int mf = (unsigned int)(kk >> 32);
    unsigned int bb = (mf & 0x80000000u) ? (mf & 0x7fffffffu) : ~mf;
    float val = __uint_as_float(bb);
    int idx = (int)(~(unsigned int)(kk & 0xffffffffu));
    sv[tid] = val;
    si[tid] = idx;
    float u = noise[(size_t)row * VV + idx];
    sg[tid] = -logf(-logf(u));
  }
  __syncthreads();

  // ---- finalize (single thread; ~few hundred ops) ----
  if (tid == 0) {
    float Z40 = 0.0f;
    #pragma unroll
    for (int w = 0; w < NT/64; w++) Z40 += wsum[w];
    const float m = sv[0];
    const float Z = Z40 * expf(40.0f - m);   // full-row softmax denominator

    int keff = (tk < 1) ? VV : tk;
    if (keff > 64) keff = 64;

    // keep set = prefix of sorted order: j < keff and cum_before < top_p
    float cum = 0.0f;
    int nk = 0;
    for (int j = 0; j < 64; j++) {
      if (j >= keff) break;
      if (!(cum < tpv)) break;
      nk++;
      cum += expf(sv[j] - m) / Z;
    }

    // logsumexp over kept (non-kept are BIG_NEG -> contribute 0)
    float Zk = 0.0f;
    for (int j = 0; j < nk; j++) Zk += expf(sv[j] - m);
    const float logZk = logf(Zk);

    // gumbel argmax over kept (first-index tie-break)
    float bv = -INFINITY; int bi = 0x7fffffff;
    for (int j = 0; j < nk; j++) {
      float val = sv[j] / t + sg[j];
      if (val > bv || (val == bv && si[j] < bi)) { bv = val; bi = si[j]; }
    }
    const int greedy = si[0];
    const int samp = (tmp < 1e-5f) ? greedy : bi;
    out[row] = (float)samp;

    // top-K logprobs + indices; fill with BIG_NEG at smallest non-kept indices
    int fi = 0;
    for (int j = 0; j < K; j++) {
      float lp; int ix;
      if (j < nk) {
        lp = (sv[j] - m) - logZk;
        ix = si[j];
      } else {
        for (;;) {
          bool kept = false;
          for (int q = 0; q < nk; q++) if (si[q] == fi) { kept = true; break; }
          if (!kept) break;
          fi++;
        }
        ix = fi; fi++;
        lp = BIG_NEG_F;
      }
      out[NB + row*K + j]          = lp;
      out[NB + NB*K + row*K + j]   = (float)ix;
    }
  }
}

extern "C" void kernel_launch(void* const* d_in, const int* in_sizes, int n_in,
                              void* d_out, int out_size, void* d_ws, size_t ws_size,
                              hipStream_t stream) {
  const float* logits   = (const float*)d_in[0];
  const int*   prompt   = (const int*)d_in[1];
  const int*   outids   = (const int*)d_in[2];
  const int*   stop     = (const int*)d_in[3];
  const int*   mint     = (const int*)d_in[4];
  const float* pres     = (const float*)d_in[5];
  const float* freq     = (const float*)d_in[6];
  const float* rep      = (const float*)d_in[7];
  const float* temp     = (const float*)d_in[8];
  const int*   topk     = (const int*)d_in[9];
  const float* topp     = (const float*)d_in[10];
  const float* noise    = (const float*)d_in[11];

  int B_ = in_sizes[4];                      // 128
  int K_ = (out_size - B_) / (2 * B_);       // 20

  sampler_kernel<<<B_, NT, 0, stream>>>(logits, prompt, outids, stop, mint,
                                        pres, freq, rep, temp, topk, topp,
                                        noise, (float*)d_out, K_);
}

// Round 2
// 245.611 us; speedup vs baseline: 2.5436x; 2.5436x over previous
//
#include <hip/hip_runtime.h>
#include <math.h>

#define VV 128000
#define NB 128
#define PP 2048
#define OO 256

#define S   5           // chunks per row
#define CH  25600       // VV/S tokens per chunk
#define CW  800         // CH/32 bitmask words
#define NT1 256
#define TC  8           // per-thread register candidates
#define CAP 512         // append-list capacity
#define HS1 512         // hash slots (count table)

#define NT2 256
#define MC  512         // merge buffer (S*64=320 padded to 512)

#define BIG_NEG_F (-1e30f)
#define PAD_KEY 0x007FFFFF80000000ULL  // packkey(-inf, 0x7fffffff)

__device__ __forceinline__ unsigned long long packkey(float f, int idx) {
  unsigned int b = __float_as_uint(f);
  unsigned int mf = (b & 0x80000000u) ? ~b : (b | 0x80000000u);
  return ((unsigned long long)mf << 32) | (unsigned long long)(unsigned int)(~(unsigned int)idx);
}
__device__ __forceinline__ float unpack_val(unsigned long long k) {
  unsigned int mf = (unsigned int)(k >> 32);
  unsigned int b = (mf & 0x80000000u) ? (mf & 0x7fffffffu) : ~mf;
  return __uint_as_float(b);
}
__device__ __forceinline__ int unpack_idx(unsigned long long k) {
  return (int)(~(unsigned int)(k & 0xffffffffu));
}

template <int N, int T>
__device__ __forceinline__ void bitonic_desc(unsigned long long* a, int tid) {
  for (int k = 2; k <= N; k <<= 1) {
    for (int j = k >> 1; j > 0; j >>= 1) {
      for (int i = tid; i < N; i += T) {
        int ixj = i ^ j;
        if (ixj > i) {
          unsigned long long x = a[i], y = a[ixj];
          bool up = (i & k) == 0;
          if ((x < y) == up) { a[i] = y; a[ixj] = x; }
        }
      }
      __syncthreads();
    }
  }
}

// ---------------- kernel 1: per-chunk penalize + exp-sum + exact top-64 ----
__global__ __launch_bounds__(NT1)
void k1_select(const float* __restrict__ logits,
               const int* __restrict__ prompt_ids,
               const int* __restrict__ output_ids,
               const int* __restrict__ stop_ids,
               const int* __restrict__ min_tokens,
               const float* __restrict__ presence_p,
               const float* __restrict__ frequency_p,
               const float* __restrict__ repetition_p,
               const float* __restrict__ temperature,
               unsigned long long* __restrict__ ws_cand,
               float* __restrict__ ws_sum)
{
#pragma clang fp contract(off)
  __shared__ unsigned int pbits[CW];
  __shared__ unsigned int obits[CW];
  __shared__ int hkey[HS1];
  __shared__ int hval[HS1];
  __shared__ unsigned long long tmax[NT1];
  __shared__ unsigned long long cand[CAP];
  __shared__ float wsum[NT1 / 64];
  __shared__ int cnt_sh;

  const int chunk = blockIdx.x;
  const int row   = blockIdx.y;
  const int tid   = threadIdx.x;
  const int base  = chunk * CH;

  const float fp  = frequency_p[row];
  const float pp  = presence_p[row];
  const float rp  = repetition_p[row];
  const float tmp = temperature[row];
  const float t   = (tmp < 1e-5f) ? 1.0f : tmp;
  const bool need = min_tokens[row] > OO;
  const int s0 = stop_ids[row * 4 + 0];
  const int s1 = stop_ids[row * 4 + 1];
  const int s2 = stop_ids[row * 4 + 2];
  const int s3 = stop_ids[row * 4 + 3];
  const bool anystop = need &&
      (((unsigned)(s0 - base) < CH) || ((unsigned)(s1 - base) < CH) ||
       ((unsigned)(s2 - base) < CH) || ((unsigned)(s3 - base) < CH));

  // init LDS
  for (int i = tid; i < CW; i += NT1) { pbits[i] = 0u; obits[i] = 0u; }
  for (int i = tid; i < HS1; i += NT1) { hkey[i] = -1; hval[i] = 0; }
  if (tid == 0) cnt_sh = 0;
  __syncthreads();

  // prompt bitmask (chunk-local)
  for (int i = tid; i < PP; i += NT1) {
    int tok = prompt_ids[row * PP + i];
    int l = tok - base;
    if ((unsigned)l < CH) atomicOr(&pbits[l >> 5], 1u << (l & 31));
  }
  // output counts: flag bitmask + small hash
  for (int i = tid; i < OO; i += NT1) {
    int tok = output_ids[row * OO + i];
    int l = tok - base;
    if ((unsigned)l < CH) {
      atomicOr(&obits[l >> 5], 1u << (l & 31));
      unsigned int h = ((unsigned int)tok * 2654435761u) >> 23;
      for (;;) {
        int k = hkey[h];
        if (k == tok) { atomicAdd(&hval[h], 1); break; }
        if (k == -1) {
          int prev = atomicCAS(&hkey[h], -1, tok);
          if (prev == -1 || prev == tok) { atomicAdd(&hval[h], 1); break; }
          continue;
        }
        h = (h + 1) & (HS1 - 1);
      }
    }
  }
  __syncthreads();

  // stream chunk: penalties + shifted exp-sum + per-thread top-8
  unsigned long long loc[TC];
#pragma unroll
  for (int c = 0; c < TC; c++) loc[c] = PAD_KEY;
  float s40 = 0.0f;

  const float* __restrict__ lrow = logits + (size_t)row * VV + base;
  for (int it = 0; it < CH / (NT1 * 4); ++it) {
    int li = (it * NT1 + tid) << 2;  // local token index, multiple of 4
    float4 xv = *(const float4*)(lrow + li);
    unsigned int w  = (unsigned)li >> 5;
    unsigned int sh = (unsigned)li & 31u;
    unsigned int pm4 = (pbits[w] >> sh) & 15u;
    unsigned int om4 = (obits[w] >> sh) & 15u;
#pragma unroll
    for (int e = 0; e < 4; ++e) {
      float x = (&xv.x)[e];
      int v = base + li + e;
      if (anystop && ((v == s0) || (v == s1) || (v == s2) || (v == s3)))
        x = fminf(x, BIG_NEG_F);
      float cnt = 0.0f;
      if ((om4 >> e) & 1u) {
        unsigned int h = ((unsigned int)v * 2654435761u) >> 23;
        for (;;) {
          int k = hkey[h];
          if (k == -1) break;
          if (k == v) { cnt = (float)hval[h]; break; }
          h = (h + 1) & (HS1 - 1);
        }
      }
      bool pm = (pm4 >> e) & 1u;
      bool om = cnt > 0.0f;
      if (pm || om) x = (x > 0.0f) ? (x / rp) : (x * rp);
      x = x - fp * cnt;
      if (om) x = x - pp;
      x = x / t;

      s40 += expf(x - 40.0f);

      unsigned long long key = packkey(x, v);
      if (key > loc[TC - 1]) {
        loc[TC - 1] = key;
#pragma unroll
        for (int q = TC - 1; q >= 1; q--) {
          if (loc[q] > loc[q - 1]) {
            unsigned long long tsw = loc[q]; loc[q] = loc[q - 1]; loc[q - 1] = tsw;
          }
        }
      }
    }
  }

  // block partial exp-sum
  float s = s40;
#pragma unroll
  for (int off = 32; off > 0; off >>= 1) s += __shfl_down(s, off, 64);
  if ((tid & 63) == 0) wsum[tid >> 6] = s;

  // threshold tau = 64th largest per-thread maximum (<= true 64th value)
  tmax[tid] = loc[0];
  __syncthreads();
  bitonic_desc<NT1, NT1>(tmax, tid);
  unsigned long long tau = tmax[63];

  // append all register candidates >= tau (exact top-64 is a subset)
#pragma unroll
  for (int c = 0; c < TC; c++) {
    if (loc[c] >= tau) {
      int p = atomicAdd(&cnt_sh, 1);
      if (p < CAP) cand[p] = loc[c];
    } else break;
  }
  __syncthreads();
  int total = cnt_sh; if (total > CAP) total = CAP;
  for (int i = tid; i < CAP; i += NT1)
    if (i >= total) cand[i] = PAD_KEY;
  __syncthreads();

  bitonic_desc<CAP, NT1>(cand, tid);

  if (tid < 64) ws_cand[((size_t)row * S + chunk) * 64 + tid] = cand[tid];
  if (tid == 0) ws_sum[row * S + chunk] = wsum[0] + wsum[1] + wsum[2] + wsum[3];
}

// ---------------- kernel 2: merge + finalize --------------------------------
__global__ __launch_bounds__(NT2)
void k2_finalize(const float* __restrict__ temperature,
                 const int* __restrict__ top_k,
                 const float* __restrict__ top_p,
                 const float* __restrict__ noise,
                 const unsigned long long* __restrict__ ws_cand,
                 const float* __restrict__ ws_sum,
                 float* __restrict__ out, int K)
{
#pragma clang fp contract(off)
  __shared__ unsigned long long cand[MC];
  __shared__ float sv[64];
  __shared__ int   si[64];
  __shared__ float se[64];
  __shared__ float gv[64];

  const int row = blockIdx.x;
  const int tid = threadIdx.x;

  const float tmp = temperature[row];
  const float t   = (tmp < 1e-5f) ? 1.0f : tmp;
  const int   tk  = top_k[row];
  const float tpv = top_p[row];

  for (int i = tid; i < MC; i += NT2)
    cand[i] = (i < S * 64) ? ws_cand[(size_t)row * S * 64 + i] : PAD_KEY;
  __syncthreads();

  bitonic_desc<MC, NT2>(cand, tid);

  if (tid < 64) {
    unsigned long long kk = cand[tid];
    float val = unpack_val(kk);
    int   idx = unpack_idx(kk);
    float m = unpack_val(cand[0]);
    sv[tid] = val;
    si[tid] = idx;
    bool ok = (unsigned)idx < VV;
    float u = ok ? noise[(size_t)row * VV + idx] : 0.5f;
    float g = -logf(-logf(u));
    se[tid] = expf(val - m);
    gv[tid] = val / t + g;
  }
  __syncthreads();

  if (tid == 0) {
    float Z40 = 0.0f;
    for (int c = 0; c < S; c++) Z40 += ws_sum[row * S + c];
    const float m = sv[0];
    const float Z = Z40 * expf(40.0f - m);  // full-row softmax denominator

    int keff = (tk < 1) ? 64 : (tk < 64 ? tk : 64);

    float cum = 0.0f;
    int nk = 0;
    for (int j = 0; j < 64; j++) {
      if (j >= keff) break;
      if (!(cum < tpv)) break;
      nk++;
      cum += se[j] / Z;
    }

    float Zk = 0.0f;
    for (int j = 0; j < nk; j++) Zk += se[j];
    const float logZk = logf(Zk);

    // gumbel argmax over kept (value desc, lowest index tie-break)
    float bv = -INFINITY; int bi = 0x7fffffff;
    for (int j = 0; j < nk; j++) {
      float val = gv[j];
      if (val > bv || (val == bv && si[j] < bi)) { bv = val; bi = si[j]; }
    }
    const int samp = (tmp < 1e-5f) ? si[0] : bi;
    out[row] = (float)samp;

    // kept-index bitmap over [0,128) for the BIG_NEG fill indices
    unsigned long long bm0 = 0ull, bm1 = 0ull;
    for (int j = 0; j < nk; j++) {
      int ix = si[j];
      if (ix < 64) bm0 |= 1ull << ix;
      else if (ix < 128) bm1 |= 1ull << (ix - 64);
    }
    int fi = 0;
    for (int j = 0; j < K; j++) {
      float lp; int ix;
      if (j < nk) {
        lp = (sv[j] - m) - logZk;
        ix = si[j];
      } else {
        while ((fi < 64) ? ((bm0 >> fi) & 1ull) : ((bm1 >> (fi - 64)) & 1ull)) fi++;
        ix = fi; fi++;
        lp = BIG_NEG_F;
      }
      out[NB + row * K + j]            = lp;
      out[NB + NB * K + row * K + j]   = (float)ix;
    }
  }
}

extern "C" void kernel_launch(void* const* d_in, const int* in_sizes, int n_in,
                              void* d_out, int out_size, void* d_ws, size_t ws_size,
                              hipStream_t stream) {
  const float* logits = (const float*)d_in[0];
  const int*   prompt = (const int*)d_in[1];
  const int*   outids = (const int*)d_in[2];
  const int*   stop   = (const int*)d_in[3];
  const int*   mint   = (const int*)d_in[4];
  const float* pres   = (const float*)d_in[5];
  const float* freq   = (const float*)d_in[6];
  const float* rep    = (const float*)d_in[7];
  const float* temp   = (const float*)d_in[8];
  const int*   topk   = (const int*)d_in[9];
  const float* topp   = (const float*)d_in[10];
  const float* noise  = (const float*)d_in[11];

  int B_ = in_sizes[4];                     // 128
  int K_ = (out_size - B_) / (2 * B_);      // 20

  unsigned long long* ws_cand = (unsigned long long*)d_ws;
  float* ws_sum = (float*)(ws_cand + (size_t)NB * S * 64);

  dim3 g1(S, B_);
  k1_select<<<g1, NT1, 0, stream>>>(logits, prompt, outids, stop, mint,
                                    pres, freq, rep, temp, ws_cand, ws_sum);
  k2_finalize<<<B_, NT2, 0, stream>>>(temp, topk, topp, noise,
                                      ws_cand, ws_sum, (float*)d_out, K_);
}

// Round 4
// 224.853 us; speedup vs baseline: 2.7785x; 1.0923x over previous
//
#include <hip/hip_runtime.h>
#include <math.h>

#define VV 128000
#define NB 128
#define PP 2048
#define OO 256

#define S   10          // chunks per row
#define CH  12800       // VV/S tokens per chunk
#define CW  400         // CH/32 bitmask words
#define NT1 256
#define CAP 256         // survivor list capacity
#define HS1 512         // hash slots (count table)

#define NT2 256
#define MC  1024        // merge buffer (S*64=640 padded to 1024)

#define BIG_NEG_F (-1e30f)
#define PAD_KEY 0x007FFFFF80000000ULL  // packkey(-inf, 0x7fffffff)
#define LOG2E 1.4426950408889634f

__device__ __forceinline__ unsigned long long packkey(float f, int idx) {
  unsigned int b = __float_as_uint(f);
  unsigned int mf = (b & 0x80000000u) ? ~b : (b | 0x80000000u);
  return ((unsigned long long)mf << 32) | (unsigned long long)(unsigned int)(~(unsigned int)idx);
}
__device__ __forceinline__ float unpack_val(unsigned long long k) {
  unsigned int mf = (unsigned int)(k >> 32);
  unsigned int b = (mf & 0x80000000u) ? (mf & 0x7fffffffu) : ~mf;
  return __uint_as_float(b);
}
__device__ __forceinline__ int unpack_idx(unsigned long long k) {
  return (int)(~(unsigned int)(k & 0xffffffffu));
}
// monotone-int float: lower f by n ulps (safe threshold slack)
__device__ __forceinline__ float ulp_down(float f, int n) {
  unsigned int b = __float_as_uint(f);
  unsigned int m = (b & 0x80000000u) ? ~b : (b | 0x80000000u);
  m -= (unsigned int)n;
  unsigned int r = (m & 0x80000000u) ? (m & 0x7fffffffu) : ~m;
  return __uint_as_float(r);
}

template <int N, int T>
__device__ __forceinline__ void bitonic_desc_u64(unsigned long long* a, int tid) {
  for (int k = 2; k <= N; k <<= 1) {
    for (int j = k >> 1; j > 0; j >>= 1) {
      for (int i = tid; i < N; i += T) {
        int ixj = i ^ j;
        if (ixj > i) {
          unsigned long long x = a[i], y = a[ixj];
          bool up = (i & k) == 0;
          if ((x < y) == up) { a[i] = y; a[ixj] = x; }
        }
      }
      __syncthreads();
    }
  }
}

template <int N, int T>
__device__ __forceinline__ void bitonic_desc_f32(float* a, int tid) {
  for (int k = 2; k <= N; k <<= 1) {
    for (int j = k >> 1; j > 0; j >>= 1) {
      for (int i = tid; i < N; i += T) {
        int ixj = i ^ j;
        if (ixj > i) {
          float x = a[i], y = a[ixj];
          bool up = (i & k) == 0;
          if ((x < y) == up) { a[i] = y; a[ixj] = x; }
        }
      }
      __syncthreads();
    }
  }
}

// ---------------- kernel 1: per-chunk penalize + exp2-sum + exact top-64 ----
__global__ __launch_bounds__(NT1)
void k1_select(const float* __restrict__ logits,
               const int* __restrict__ prompt_ids,
               const int* __restrict__ output_ids,
               const int* __restrict__ stop_ids,
               const int* __restrict__ min_tokens,
               const float* __restrict__ presence_p,
               const float* __restrict__ frequency_p,
               const float* __restrict__ repetition_p,
               const float* __restrict__ temperature,
               unsigned long long* __restrict__ ws_cand,
               float* __restrict__ ws_sum)
{
#pragma clang fp contract(off)
  __shared__ unsigned int pbits[CW];
  __shared__ unsigned int obits[CW];
  __shared__ int hkey[HS1];
  __shared__ int hval[HS1];
  __shared__ float tmax[NT1];
  __shared__ unsigned long long cand[CAP];
  __shared__ float wsum[NT1 / 64];
  __shared__ int cnt_sh;

  const int chunk = blockIdx.x;
  const int row   = blockIdx.y;
  const int tid   = threadIdx.x;
  const int base  = chunk * CH;

  const float fp  = frequency_p[row];
  const float pp  = presence_p[row];
  const float rp  = repetition_p[row];
  const float inv_rp = 1.0f / rp;          // approx mul path (phase A only)
  const float tmp = temperature[row];
  const float t   = (tmp < 1e-5f) ? 1.0f : tmp;
  const float c2  = LOG2E / t;             // exp(x/t) = exp2(x*c2)
  const bool need = min_tokens[row] > OO;
  const int s0 = stop_ids[row * 4 + 0];
  const int s1 = stop_ids[row * 4 + 1];
  const int s2 = stop_ids[row * 4 + 2];
  const int s3 = stop_ids[row * 4 + 3];
  const bool anystop = need &&
      (((unsigned)(s0 - base) < CH) || ((unsigned)(s1 - base) < CH) ||
       ((unsigned)(s2 - base) < CH) || ((unsigned)(s3 - base) < CH));

  // init LDS
  for (int i = tid; i < CW; i += NT1) { pbits[i] = 0u; obits[i] = 0u; }
  for (int i = tid; i < HS1; i += NT1) { hkey[i] = -1; hval[i] = 0; }
  if (tid == 0) cnt_sh = 0;
  __syncthreads();

  // prompt bitmask (chunk-local)
  for (int i = tid; i < PP; i += NT1) {
    int tok = prompt_ids[row * PP + i];
    int l = tok - base;
    if ((unsigned)l < CH) atomicOr(&pbits[l >> 5], 1u << (l & 31));
  }
  // output counts: flag bitmask + small hash
  for (int i = tid; i < OO; i += NT1) {
    int tok = output_ids[row * OO + i];
    int l = tok - base;
    if ((unsigned)l < CH) {
      atomicOr(&obits[l >> 5], 1u << (l & 31));
      unsigned int h = ((unsigned int)tok * 2654435761u) >> 23;
      for (;;) {
        int k = hkey[h];
        if (k == tok) { atomicAdd(&hval[h], 1); break; }
        if (k == -1) {
          int prev = atomicCAS(&hkey[h], -1, tok);
          if (prev == -1 || prev == tok) { atomicAdd(&hval[h], 1); break; }
          continue;
        }
        h = (h + 1) & (HS1 - 1);
      }
    }
  }
  __syncthreads();

  const float* __restrict__ lrow = logits + (size_t)row * VV + base;

  // ---- phase A: scalar max + exp2 sum (approx penalty: mul instead of div)
  float mx = -INFINITY;
  float esum = 0.0f;
  for (int it = 0; it < (CH + NT1 * 4 - 1) / (NT1 * 4); ++it) {
    int li = (it * NT1 + tid) << 2;
    if (li >= CH) break;
    float4 xv = *(const float4*)(lrow + li);
    unsigned int w  = (unsigned)li >> 5;
    unsigned int sh = (unsigned)li & 31u;
    unsigned int pm4 = (pbits[w] >> sh) & 15u;
    unsigned int om4 = (obits[w] >> sh) & 15u;
#pragma unroll
    for (int e = 0; e < 4; ++e) {
      float x = (&xv.x)[e];
      int v = base + li + e;
      float xp = x;
      if (anystop && ((v == s0) | (v == s1) | (v == s2) | (v == s3)))
        xp = BIG_NEG_F;
      if ((pm4 | om4) & (1u << e)) {
        xp = (xp > 0.0f) ? (xp * inv_rp) : (xp * rp);
        if ((om4 >> e) & 1u) {
          float cnt = 0.0f;
          unsigned int h = ((unsigned int)v * 2654435761u) >> 23;
          for (;;) {
            int k = hkey[h];
            if (k == -1) break;
            if (k == v) { cnt = (float)hval[h]; break; }
            h = (h + 1) & (HS1 - 1);
          }
          xp = xp - fp * cnt - pp;
        }
      }
      mx = fmaxf(mx, xp);
      esum += exp2f(xp * c2);
    }
  }

  // block partial exp-sum (exp2 domain, un-shifted)
  float s = esum;
#pragma unroll
  for (int off = 32; off > 0; off >>= 1) s += __shfl_down(s, off, 64);
  if ((tid & 63) == 0) wsum[tid >> 6] = s;

  // tau = 64th largest per-thread max (<= true 64th value), minus 8 ulps slack
  tmax[tid] = mx;
  __syncthreads();
  bitonic_desc_f32<NT1, NT1>(tmax, tid);
  const float tau = ulp_down(tmax[63], 8);
  __syncthreads();

  // ---- phase B: re-stream (L2-warm); raw-filter then exact recompute ----
  for (int it = 0; it < (CH + NT1 * 4 - 1) / (NT1 * 4); ++it) {
    int li = (it * NT1 + tid) << 2;
    if (li >= CH) break;
    float4 xv = *(const float4*)(lrow + li);
#pragma unroll
    for (int e = 0; e < 4; ++e) {
      float x = (&xv.x)[e];
      if (x >= tau) {   // penalties only decrease x -> safe superset
        int v = base + li + e;
        // exact recompute, reference op order
        if (anystop && ((v == s0) | (v == s1) | (v == s2) | (v == s3)))
          x = fminf(x, BIG_NEG_F);
        unsigned int w  = (unsigned)(li + e) >> 5;
        unsigned int sh = (unsigned)(li + e) & 31u;
        bool pm = (pbits[w] >> sh) & 1u;
        bool om = (obits[w] >> sh) & 1u;
        float cnt = 0.0f;
        if (om) {
          unsigned int h = ((unsigned int)v * 2654435761u) >> 23;
          for (;;) {
            int k = hkey[h];
            if (k == -1) break;
            if (k == v) { cnt = (float)hval[h]; break; }
            h = (h + 1) & (HS1 - 1);
          }
        }
        if (pm || om) x = (x > 0.0f) ? (x / rp) : (x * rp);
        x = x - fp * cnt;
        if (om) x = x - pp;
        if (x >= tau) {          // still in (un-divided) threshold domain
          float xd = x / t;      // exact, matches reference finalist values
          int p = atomicAdd(&cnt_sh, 1);
          if (p < CAP) cand[p] = packkey(xd, v);
        }
      }
    }
  }
  __syncthreads();
  int total = cnt_sh; if (total > CAP) total = CAP;
  for (int i = tid; i < CAP; i += NT1)
    if (i >= total) cand[i] = PAD_KEY;
  __syncthreads();

  bitonic_desc_u64<CAP, NT1>(cand, tid);

  if (tid < 64) ws_cand[((size_t)row * S + chunk) * 64 + tid] = cand[tid];
  if (tid == 0) ws_sum[row * S + chunk] = wsum[0] + wsum[1] + wsum[2] + wsum[3];
}

// ---------------- kernel 2: merge + finalize --------------------------------
__global__ __launch_bounds__(NT2)
void k2_finalize(const float* __restrict__ temperature,
                 const int* __restrict__ top_k,
                 const float* __restrict__ top_p,
                 const float* __restrict__ noise,
                 const unsigned long long* __restrict__ ws_cand,
                 const float* __restrict__ ws_sum,
                 float* __restrict__ out, int K)
{
#pragma clang fp contract(off)
  __shared__ unsigned long long cand[MC];
  __shared__ float sv[64];
  __shared__ int   si[64];
  __shared__ float se[64];
  __shared__ float gv[64];

  const int row = blockIdx.x;
  const int tid = threadIdx.x;

  const float tmp = temperature[row];
  const float t   = (tmp < 1e-5f) ? 1.0f : tmp;
  const int   tk  = top_k[row];
  const float tpv = top_p[row];

  for (int i = tid; i < MC; i += NT2)
    cand[i] = (i < S * 64) ? ws_cand[(size_t)row * S * 64 + i] : PAD_KEY;
  __syncthreads();

  bitonic_desc_u64<MC, NT2>(cand, tid);

  if (tid < 64) {
    unsigned long long kk = cand[tid];
    float val = unpack_val(kk);
    int   idx = unpack_idx(kk);
    float m = unpack_val(cand[0]);
    sv[tid] = val;
    si[tid] = idx;
    bool ok = (unsigned)idx < VV;
    float u = ok ? noise[(size_t)row * VV + idx] : 0.5f;
    float g = -logf(-logf(u));
    se[tid] = expf(val - m);
    gv[tid] = val / t + g;
  }
  __syncthreads();

  if (tid == 0) {
    float Ssum = 0.0f;
    for (int c = 0; c < S; c++) Ssum += ws_sum[row * S + c];
    const float m = sv[0];
    // Z relative to max m (divided domain): sum exp2(x*c2) * 2^(-m*log2e)
    const float Z = Ssum * exp2f(-m * LOG2E);

    int keff = (tk < 1) ? 64 : (tk < 64 ? tk : 64);

    float cum = 0.0f;
    int nk = 0;
    for (int j = 0; j < 64; j++) {
      if (j >= keff) break;
      if (!(cum < tpv)) break;
      nk++;
      cum += se[j] / Z;
    }

    float Zk = 0.0f;
    for (int j = 0; j < nk; j++) Zk += se[j];
    const float logZk = logf(Zk);

    // gumbel argmax over kept (value desc, lowest index tie-break)
    float bv = -INFINITY; int bi = 0x7fffffff;
    for (int j = 0; j < nk; j++) {
      float val = gv[j];
      if (val > bv || (val == bv && si[j] < bi)) { bv = val; bi = si[j]; }
    }
    const int samp = (tmp < 1e-5f) ? si[0] : bi;
    out[row] = (float)samp;

    // kept-index bitmap over [0,128) for the BIG_NEG fill indices
    unsigned long long bm0 = 0ull, bm1 = 0ull;
    for (int j = 0; j < nk; j++) {
      int ix = si[j];
      if (ix < 64) bm0 |= 1ull << ix;
      else if (ix < 128) bm1 |= 1ull << (ix - 64);
    }
    int fi = 0;
    for (int j = 0; j < K; j++) {
      float lp; int ix;
      if (j < nk) {
        lp = (sv[j] - m) - logZk;
        ix = si[j];
      } else {
        while ((fi < 64) ? ((bm0 >> fi) & 1ull) : ((bm1 >> (fi - 64)) & 1ull)) fi++;
        ix = fi; fi++;
        lp = BIG_NEG_F;
      }
      out[NB + row * K + j]            = lp;
      out[NB + NB * K + row * K + j]   = (float)ix;
    }
  }
}

extern "C" void kernel_launch(void* const* d_in, const int* in_sizes, int n_in,
                              void* d_out, int out_size, void* d_ws, size_t ws_size,
                              hipStream_t stream) {
  const float* logits = (const float*)d_in[0];
  const int*   prompt = (const int*)d_in[1];
  const int*   outids = (const int*)d_in[2];
  const int*   stop   = (const int*)d_in[3];
  const int*   mint   = (const int*)d_in[4];
  const float* pres   = (const float*)d_in[5];
  const float* freq   = (const float*)d_in[6];
  const float* rep    = (const float*)d_in[7];
  const float* temp   = (const float*)d_in[8];
  const int*   topk   = (const int*)d_in[9];
  const float* topp   = (const float*)d_in[10];
  const float* noise  = (const float*)d_in[11];

  int B_ = in_sizes[4];                     // 128
  int K_ = (out_size - B_) / (2 * B_);      // 20

  unsigned long long* ws_cand = (unsigned long long*)d_ws;
  float* ws_sum = (float*)(ws_cand + (size_t)NB * S * 64);

  dim3 g1(S, B_);
  k1_select<<<g1, NT1, 0, stream>>>(logits, prompt, outids, stop, mint,
                                    pres, freq, rep, temp, ws_cand, ws_sum);
  k2_finalize<<<B_, NT2, 0, stream>>>(temp, topk, topp, noise,
                                      ws_cand, ws_sum, (float*)d_out, K_);
}